// Round 1
// baseline (1524.249 us; speedup 1.0000x reference)
//
#include <hip/hip_runtime.h>

// ConvBlock5: pool(scatter) -> conv(gemm+scatter) x2 -> unpool(scatter)
// C = 64 channels, fp32 throughout.

#define NCH 64

// ---------------------------------------------------------------------------
// Scatter: for each edge e: out[dst[e]][c] += in[src[e]][c] * attr[e]
// One wave (64 lanes) per edge; lane == channel. Gather and atomic target are
// each one contiguous 256 B row -> fully coalesced. src/dst/attr are
// wave-uniform loads (HW broadcast). unsafeAtomicAdd -> global_atomic_add_f32.
// ---------------------------------------------------------------------------
__global__ __launch_bounds__(256) void scatter_edge_kernel(
    const float* __restrict__ in, float* __restrict__ out,
    const int* __restrict__ src, const int* __restrict__ dst,
    const float* __restrict__ attr, int nE) {
  int tid = blockIdx.x * blockDim.x + threadIdx.x;
  int e = tid >> 6;
  int c = tid & 63;
  if (e >= nE) return;
  int s = src[e];
  int d = dst[e];
  float a = attr[e];
  float v = in[s * NCH + c] * a;
  unsafeAtomicAdd(&out[d * NCH + c], v);
}

// ---------------------------------------------------------------------------
// Per-node dual GEMM: out_r[i,:] = h[i,:] @ Wr + bias ; out_n[i,:] = h[i,:] @ Wn
// One wave per row, lane == output channel. Both 64x64 weight columns live in
// registers (128 VGPRs/lane, loaded once per wave); the row value h[i,k] is
// broadcast with v_readlane (SGPR) -> zero LDS traffic in the inner loop.
// 64 readlane + 128 FMA per row per lane.
// ---------------------------------------------------------------------------
__global__ __launch_bounds__(256) void node_gemm_kernel(
    const float* __restrict__ h, const float* __restrict__ Wr,
    const float* __restrict__ Wn, const float* __restrict__ bias,
    float* __restrict__ out_r, float* __restrict__ out_n, int n) {
  const int lane = threadIdx.x & 63;

  float wr[64], wn[64];
#pragma unroll
  for (int k = 0; k < 64; ++k) {
    wr[k] = Wr[k * NCH + lane];  // W[k][c], c = lane
    wn[k] = Wn[k * NCH + lane];
  }
  const float bv = bias[lane];

  const int wave = (blockIdx.x * blockDim.x + threadIdx.x) >> 6;
  const int nwaves = (gridDim.x * blockDim.x) >> 6;

  for (int i = wave; i < n; i += nwaves) {
    float v = h[i * NCH + lane];
    float ar = bv;
    float an = 0.0f;
#pragma unroll
    for (int k = 0; k < 64; ++k) {
      float s = __uint_as_float(
          __builtin_amdgcn_readlane(__float_as_uint(v), k));
      ar = __builtin_fmaf(s, wr[k], ar);
      an = __builtin_fmaf(s, wn[k], an);
    }
    out_r[i * NCH + lane] = ar;
    out_n[i * NCH + lane] = an;
  }
}

extern "C" void kernel_launch(void* const* d_in, const int* in_sizes, int n_in,
                              void* d_out, int out_size, void* d_ws,
                              size_t ws_size, hipStream_t stream) {
  const float* x = (const float*)d_in[0];
  const float* W1r = (const float*)d_in[1];
  const float* W1n = (const float*)d_in[2];
  const float* b1 = (const float*)d_in[3];
  const float* W2r = (const float*)d_in[4];
  const float* W2n = (const float*)d_in[5];
  const float* b2 = (const float*)d_in[6];
  const int* pool_src = (const int*)d_in[7];
  const int* pool_dst = (const int*)d_in[8];
  const float* pool_attr = (const float*)d_in[9];
  const int* conv_src = (const int*)d_in[10];
  const int* conv_dst = (const int*)d_in[11];
  const float* conv_attr = (const float*)d_in[12];
  const int* unpool_src = (const int*)d_in[13];
  const int* unpool_dst = (const int*)d_in[14];
  const float* unpool_attr = (const float*)d_in[15];

  const int Ep = in_sizes[7];
  const int Ec = in_sizes[10];
  const int Eu = in_sizes[13];
  // n_coarse lives on-device as a scalar; the problem size is fixed.
  const int n_coarse = 100000;

  const size_t bufElems = (size_t)n_coarse * NCH;  // 6.4M floats = 25.6 MB
  float* bufA = (float*)d_ws;
  float* bufB = bufA + bufElems;
  // bufC: prefer ws; fall back into d_out's storage (d_out is only zeroed
  // right before the final unpool scatter, after bufC's last use).
  float* bufC = (ws_size >= 3 * bufElems * sizeof(float))
                    ? (bufB + bufElems)
                    : (float*)d_out;

  const dim3 blk(256);
  const int gemm_grid = 2048;  // 8192 waves, grid-stride over 100K rows

  // xc accumulator must start at zero (ws is poisoned each call).
  hipMemsetAsync(bufA, 0, bufElems * sizeof(float), stream);

  // 1. pool: x -> bufA (xc)
  scatter_edge_kernel<<<dim3((unsigned)((Ep * 64 + 255) / 256)), blk, 0,
                        stream>>>(x, bufA, pool_src, pool_dst, pool_attr, Ep);

  // 2. conv1 gemm: bufA -> bufC (root + bias), bufB (neighbor transform)
  node_gemm_kernel<<<dim3(gemm_grid), blk, 0, stream>>>(bufA, W1r, W1n, b1,
                                                        bufC, bufB, n_coarse);
  // 3. conv1 message scatter: bufB -> bufC  (h1 complete in bufC)
  scatter_edge_kernel<<<dim3((unsigned)((Ec * 64 + 255) / 256)), blk, 0,
                        stream>>>(bufB, bufC, conv_src, conv_dst, conv_attr,
                                  Ec);

  // 4. conv2 gemm: bufC -> bufA (root + bias), bufB (neighbor transform)
  node_gemm_kernel<<<dim3(gemm_grid), blk, 0, stream>>>(bufC, W2r, W2n, b2,
                                                        bufA, bufB, n_coarse);
  // 5. conv2 message scatter: bufB -> bufA  (h2 complete in bufA)
  scatter_edge_kernel<<<dim3((unsigned)((Ec * 64 + 255) / 256)), blk, 0,
                        stream>>>(bufB, bufA, conv_src, conv_dst, conv_attr,
                                  Ec);

  // 6. unpool: zero output, then bufA -> d_out
  hipMemsetAsync(d_out, 0, (size_t)out_size * sizeof(float), stream);
  scatter_edge_kernel<<<dim3((unsigned)((Eu * 64 + 255) / 256)), blk, 0,
                        stream>>>(bufA, (float*)d_out, unpool_src, unpool_dst,
                                  unpool_attr, Eu);
}

// Round 2
// 1356.609 us; speedup vs baseline: 1.1236x; 1.1236x over previous
//
#include <hip/hip_runtime.h>

// ConvBlock5: pool -> conv x2 -> unpool, C=64 fp32.
// Round 2: replace all atomic scatters with per-call CSR build + gather-reduce
// (one wave per destination node, lane = channel, register accumulation).
// Rationale: round-1 counters showed WRITE_SIZE == edges*256B exactly --
// device-scope fp atomics bypass L2, so scatter writes got zero cache
// absorption (1.9 TB/s fabric-bound, 352us per conv scatter).

#define NCH 64

// ---------------------------------------------------------------------------
// CSR build: hist -> 3-kernel exclusive scan (in-place cnt->rowptr) -> permute
// ---------------------------------------------------------------------------

__global__ __launch_bounds__(256) void hist_kernel(const int* __restrict__ dst,
                                                   int* __restrict__ cnt,
                                                   int nE) {
  int e = blockIdx.x * blockDim.x + threadIdx.x;
  if (e < nE) atomicAdd(&cnt[dst[e]], 1);
}

static __device__ __forceinline__ int wave_incl_scan(int v, int lane) {
#pragma unroll
  for (int off = 1; off < 64; off <<= 1) {
    int t = __shfl_up(v, off, 64);
    if (lane >= off) v += t;
  }
  return v;
}

// Per-block (2048 elems) reduction into bsums.
__global__ __launch_bounds__(256) void scan_reduce(const int* __restrict__ cnt,
                                                   int* __restrict__ bsums,
                                                   int n) {
  int base = blockIdx.x * 2048 + threadIdx.x * 8;
  int s = 0;
#pragma unroll
  for (int j = 0; j < 8; ++j) {
    int idx = base + j;
    s += (idx < n) ? cnt[idx] : 0;
  }
  int lane = threadIdx.x & 63;
  int w = threadIdx.x >> 6;
#pragma unroll
  for (int off = 32; off; off >>= 1) s += __shfl_xor(s, off, 64);
  __shared__ int ws_[4];
  if (lane == 0) ws_[w] = s;
  __syncthreads();
  if (threadIdx.x == 0) bsums[blockIdx.x] = ws_[0] + ws_[1] + ws_[2] + ws_[3];
}

// Single-wave exclusive scan of block sums (nB <= ~200).
__global__ void scan_bsums(int* __restrict__ bs, int nB) {
  int lane = threadIdx.x;  // launched with 64 threads
  int carry = 0;
  for (int base = 0; base < nB; base += 64) {
    int i = base + lane;
    int orig = (i < nB) ? bs[i] : 0;
    int v = wave_incl_scan(orig, lane);
    if (i < nB) bs[i] = v - orig + carry;
    carry += __shfl(v, 63, 64);
  }
}

// In-place exclusive scan: cnt[0..n) -> rowptr[0..n]. Each thread owns 8
// consecutive idx (reads its own 8 before writing them -> in-place safe).
__global__ __launch_bounds__(256) void scan_final(int* __restrict__ cnt_rowptr,
                                                  const int* __restrict__ bsums,
                                                  int n) {
  int base = blockIdx.x * 2048 + threadIdx.x * 8;
  int v[8];
  int s = 0;
#pragma unroll
  for (int j = 0; j < 8; ++j) {
    int idx = base + j;
    v[j] = (idx < n) ? cnt_rowptr[idx] : 0;
    s += v[j];
  }
  int lane = threadIdx.x & 63;
  int w = threadIdx.x >> 6;
  int inc = wave_incl_scan(s, lane);
  __shared__ int wsum[4];
  if (lane == 63) wsum[w] = inc;
  __syncthreads();
  int woff = 0;
  for (int ww = 0; ww < w; ++ww) woff += wsum[ww];
  int excl = inc - s + woff + bsums[blockIdx.x];
#pragma unroll
  for (int j = 0; j < 8; ++j) {
    int idx = base + j;
    if (idx <= n) cnt_rowptr[idx] = excl;
    excl += v[j];
  }
}

// Scatter edge payloads into CSR order. cursor = copy of rowptr[0..nDst).
__global__ __launch_bounds__(256) void permute_kernel(
    const int* __restrict__ src, const int* __restrict__ dst,
    const float* __restrict__ attr, int* __restrict__ cursor,
    int2* __restrict__ payload, int nE) {
  int e = blockIdx.x * blockDim.x + threadIdx.x;
  if (e >= nE) return;
  int p = atomicAdd(&cursor[dst[e]], 1);
  payload[p] = make_int2(src[e], __float_as_int(attr[e]));
}

// ---------------------------------------------------------------------------
// Gather-reduce: one wave per dst node, lane = channel. No atomics.
// accumulate=1: out += sum (out already holds root+bias); else out = sum.
// ---------------------------------------------------------------------------
__global__ __launch_bounds__(256) void gather_kernel(
    const float* __restrict__ in, const int* __restrict__ rowptr,
    const int2* __restrict__ payload, float* __restrict__ out, int nDst,
    int accumulate) {
  int wave = (blockIdx.x * blockDim.x + threadIdx.x) >> 6;
  int lane = threadIdx.x & 63;
  if (wave >= nDst) return;
  int beg = rowptr[wave];
  int end = rowptr[wave + 1];
  float acc = 0.0f;
  for (int j = beg; j < end; ++j) {
    int2 pl = payload[j];  // wave-uniform 8B load (HW broadcast)
    acc = __builtin_fmaf(in[(size_t)pl.x * NCH + lane],
                         __int_as_float(pl.y), acc);
  }
  size_t o = (size_t)wave * NCH + lane;
  if (accumulate)
    out[o] += acc;
  else
    out[o] = acc;
}

// ---------------------------------------------------------------------------
// Per-node dual GEMM: out_r = h @ Wr + b ; out_n = h @ Wn.
// One wave per row; both 64x64 weights in registers; readlane broadcast.
// ---------------------------------------------------------------------------
__global__ __launch_bounds__(256) void node_gemm_kernel(
    const float* __restrict__ h, const float* __restrict__ Wr,
    const float* __restrict__ Wn, const float* __restrict__ bias,
    float* __restrict__ out_r, float* __restrict__ out_n, int n) {
  const int lane = threadIdx.x & 63;

  float wr[64], wn[64];
#pragma unroll
  for (int k = 0; k < 64; ++k) {
    wr[k] = Wr[k * NCH + lane];
    wn[k] = Wn[k * NCH + lane];
  }
  const float bv = bias[lane];

  const int wave = (blockIdx.x * blockDim.x + threadIdx.x) >> 6;
  const int nwaves = (gridDim.x * blockDim.x) >> 6;

  for (int i = wave; i < n; i += nwaves) {
    float v = h[(size_t)i * NCH + lane];
    float ar = bv;
    float an = 0.0f;
#pragma unroll
    for (int k = 0; k < 64; ++k) {
      float s =
          __uint_as_float(__builtin_amdgcn_readlane(__float_as_uint(v), k));
      ar = __builtin_fmaf(s, wr[k], ar);
      an = __builtin_fmaf(s, wn[k], an);
    }
    out_r[(size_t)i * NCH + lane] = ar;
    out_n[(size_t)i * NCH + lane] = an;
  }
}

extern "C" void kernel_launch(void* const* d_in, const int* in_sizes, int n_in,
                              void* d_out, int out_size, void* d_ws,
                              size_t ws_size, hipStream_t stream) {
  const float* x = (const float*)d_in[0];
  const float* W1r = (const float*)d_in[1];
  const float* W1n = (const float*)d_in[2];
  const float* b1 = (const float*)d_in[3];
  const float* W2r = (const float*)d_in[4];
  const float* W2n = (const float*)d_in[5];
  const float* b2 = (const float*)d_in[6];
  const int* pool_src = (const int*)d_in[7];
  const int* pool_dst = (const int*)d_in[8];
  const float* pool_attr = (const float*)d_in[9];
  const int* conv_src = (const int*)d_in[10];
  const int* conv_dst = (const int*)d_in[11];
  const float* conv_attr = (const float*)d_in[12];
  const int* unpool_src = (const int*)d_in[13];
  const int* unpool_dst = (const int*)d_in[14];
  const float* unpool_attr = (const float*)d_in[15];

  const int Ep = in_sizes[7];
  const int Ec = in_sizes[10];
  const int Eu = in_sizes[13];
  const int NC = 100000;  // n_coarse (fixed problem size)
  const int NF = 400000;  // n_fine

  const size_t MiB = 1024u * 1024u;

  // ws layout (needs ~38 MiB; round-1 established ws >= 51.2e6 B):
  //   bufA (h buffers, final h2)        @ 0      24.4 MiB
  //   up_rp (unpool rowptr, NF+1 ints)  @ 26MiB   1.6 MiB
  //   up_pl (unpool payload, Eu int2)   @ 28MiB   9.2 MiB
  char* ws = (char*)d_ws;
  float* bufA = (float*)ws;
  int* up_rp = (int*)(ws + 26 * MiB);
  int2* up_pl = (int2*)(ws + 28 * MiB);

  // d_out doubles as scratch for everything dead before the final unpool
  // gather (which overwrites all of d_out). 97.6 MiB available:
  char* ob = (char*)d_out;
  float* bufB = (float*)ob;              // 24.4 MiB
  float* bufC = (float*)(ob + 26 * MiB); // 24.4 MiB
  int* cv_rp = (int*)(ob + 52 * MiB);    // 0.4 MiB (NC+1 ints)
  int2* cv_pl = (int2*)(ob + 53 * MiB);  // 12.2 MiB (Ec int2)
  int* pl_rp = (int*)(ob + 66 * MiB);    // 0.4 MiB
  int2* pl_pl = (int2*)(ob + 67 * MiB);  // 9.2 MiB
  int* cursor = (int*)(ob + 77 * MiB);   // 1.6 MiB (max NF ints)
  int* bsums = (int*)(ob + 79 * MiB);    // ~1 KiB

  const dim3 blk(256);

  auto build_csr = [&](const int* srcA, const int* dstA, const float* attrA,
                       int nE, int nDst, int* rp, int2* pl) {
    int nB = (nDst + 1 + 2047) / 2048;
    hipMemsetAsync(rp, 0, (size_t)(nDst + 1) * sizeof(int), stream);
    hist_kernel<<<dim3((nE + 255) / 256), blk, 0, stream>>>(dstA, rp, nE);
    scan_reduce<<<dim3(nB), blk, 0, stream>>>(rp, bsums, nDst);
    scan_bsums<<<dim3(1), dim3(64), 0, stream>>>(bsums, nB);
    scan_final<<<dim3(nB), blk, 0, stream>>>(rp, bsums, nDst);
    hipMemcpyAsync(cursor, rp, (size_t)nDst * sizeof(int),
                   hipMemcpyDeviceToDevice, stream);
    permute_kernel<<<dim3((nE + 255) / 256), blk, 0, stream>>>(
        srcA, dstA, attrA, cursor, pl, nE);
  };

  // Build all three CSRs up front (only depend on edge arrays).
  build_csr(pool_src, pool_dst, pool_attr, Ep, NC, pl_rp, pl_pl);
  build_csr(conv_src, conv_dst, conv_attr, Ec, NC, cv_rp, cv_pl);
  build_csr(unpool_src, unpool_dst, unpool_attr, Eu, NF, up_rp, up_pl);

  const int gemm_grid = 2048;

  // 1. pool: xc = gather(x) -> bufA (writes every row; no memset needed)
  gather_kernel<<<dim3(NC / 4), blk, 0, stream>>>(x, pl_rp, pl_pl, bufA, NC, 0);

  // 2. conv1: gemm bufA -> bufC(root+bias), bufB(nb); gather bufB += into bufC
  node_gemm_kernel<<<dim3(gemm_grid), blk, 0, stream>>>(bufA, W1r, W1n, b1,
                                                        bufC, bufB, NC);
  gather_kernel<<<dim3(NC / 4), blk, 0, stream>>>(bufB, cv_rp, cv_pl, bufC, NC,
                                                  1);

  // 3. conv2: gemm bufC -> bufA(root+bias), bufB(nb); gather bufB += into bufA
  node_gemm_kernel<<<dim3(gemm_grid), blk, 0, stream>>>(bufC, W2r, W2n, b2,
                                                        bufA, bufB, NC);
  gather_kernel<<<dim3(NC / 4), blk, 0, stream>>>(bufB, cv_rp, cv_pl, bufA, NC,
                                                  1);

  // 4. unpool: d_out = gather(bufA). Reads only ws; overwrites all of d_out
  //    (zero rows for empty segments -> no memset needed).
  gather_kernel<<<dim3(NF / 4), blk, 0, stream>>>(bufA, up_rp, up_pl,
                                                  (float*)d_out, NF, 0);
}

// Round 3
// 1050.332 us; speedup vs baseline: 1.4512x; 1.2916x over previous
//
#include <hip/hip_runtime.h>

// ConvBlock5: pool -> conv x2 -> unpool, C=64 fp32.
// Round 3:
//  - gather4: 16 lanes/edge, float4/lane, 4 edges per load instr, chunk=16
//    (4 independent row-gathers in flight -> MLP 4x; round-2 profile showed
//    ~1480 cyc/edge serial chain, VALUBusy 11%, 14% HBM = latency-bound).
//  - linearity fusion: segment_sum((h@Wn)[src]*a) == segment_sum(h[src]*a)@Wn,
//    so gather raw h, then one fused gemm h' = h@Wr + g@Wn + b (kills the
//    separate neighbor-transform pass and the RMW accumulate).

#define NCH 64

// ---------------------------------------------------------------------------
// CSR build: hist -> 3-kernel exclusive scan (in-place cnt->rowptr) -> permute
// ---------------------------------------------------------------------------

__global__ __launch_bounds__(256) void hist_kernel(const int* __restrict__ dst,
                                                   int* __restrict__ cnt,
                                                   int nE) {
  int e = blockIdx.x * blockDim.x + threadIdx.x;
  if (e < nE) atomicAdd(&cnt[dst[e]], 1);
}

static __device__ __forceinline__ int wave_incl_scan(int v, int lane) {
#pragma unroll
  for (int off = 1; off < 64; off <<= 1) {
    int t = __shfl_up(v, off, 64);
    if (lane >= off) v += t;
  }
  return v;
}

__global__ __launch_bounds__(256) void scan_reduce(const int* __restrict__ cnt,
                                                   int* __restrict__ bsums,
                                                   int n) {
  int base = blockIdx.x * 2048 + threadIdx.x * 8;
  int s = 0;
#pragma unroll
  for (int j = 0; j < 8; ++j) {
    int idx = base + j;
    s += (idx < n) ? cnt[idx] : 0;
  }
  int lane = threadIdx.x & 63;
  int w = threadIdx.x >> 6;
#pragma unroll
  for (int off = 32; off; off >>= 1) s += __shfl_xor(s, off, 64);
  __shared__ int ws_[4];
  if (lane == 0) ws_[w] = s;
  __syncthreads();
  if (threadIdx.x == 0) bsums[blockIdx.x] = ws_[0] + ws_[1] + ws_[2] + ws_[3];
}

__global__ void scan_bsums(int* __restrict__ bs, int nB) {
  int lane = threadIdx.x;  // 64 threads
  int carry = 0;
  for (int base = 0; base < nB; base += 64) {
    int i = base + lane;
    int orig = (i < nB) ? bs[i] : 0;
    int v = wave_incl_scan(orig, lane);
    if (i < nB) bs[i] = v - orig + carry;
    carry += __shfl(v, 63, 64);
  }
}

__global__ __launch_bounds__(256) void scan_final(int* __restrict__ cnt_rowptr,
                                                  const int* __restrict__ bsums,
                                                  int n) {
  int base = blockIdx.x * 2048 + threadIdx.x * 8;
  int v[8];
  int s = 0;
#pragma unroll
  for (int j = 0; j < 8; ++j) {
    int idx = base + j;
    v[j] = (idx < n) ? cnt_rowptr[idx] : 0;
    s += v[j];
  }
  int lane = threadIdx.x & 63;
  int w = threadIdx.x >> 6;
  int inc = wave_incl_scan(s, lane);
  __shared__ int wsum[4];
  if (lane == 63) wsum[w] = inc;
  __syncthreads();
  int woff = 0;
  for (int ww = 0; ww < w; ++ww) woff += wsum[ww];
  int excl = inc - s + woff + bsums[blockIdx.x];
#pragma unroll
  for (int j = 0; j < 8; ++j) {
    int idx = base + j;
    if (idx <= n) cnt_rowptr[idx] = excl;
    excl += v[j];
  }
}

__global__ __launch_bounds__(256) void permute_kernel(
    const int* __restrict__ src, const int* __restrict__ dst,
    const float* __restrict__ attr, int* __restrict__ cursor,
    int2* __restrict__ payload, int nE) {
  int e = blockIdx.x * blockDim.x + threadIdx.x;
  if (e >= nE) return;
  int p = atomicAdd(&cursor[dst[e]], 1);
  payload[p] = make_int2(src[e], __float_as_int(attr[e]));
}

// ---------------------------------------------------------------------------
// Gather-reduce, MLP=4: one wave per dst node; 16 lanes per edge, float4 per
// lane (16B). Each iteration handles a chunk of 16 edges as 4 groups-of-4 with
// 4 independent payload loads + 4 independent row gathers in flight.
// Inactive edge slots read row 0 with weight 0 (harmless, cached).
// ---------------------------------------------------------------------------
__global__ __launch_bounds__(256) void gather4_kernel(
    const float* __restrict__ in, const int* __restrict__ rowptr,
    const int2* __restrict__ payload, float* __restrict__ out, int nDst) {
  const int wid = (blockIdx.x * blockDim.x + threadIdx.x) >> 6;
  const int lane = threadIdx.x & 63;
  if (wid >= nDst) return;
  const int beg = rowptr[wid];
  const int end = rowptr[wid + 1];
  const int g = lane >> 4;         // edge group 0..3
  const int cq = (lane & 15) * 4;  // channel quad base

  float4 acc = make_float4(0.f, 0.f, 0.f, 0.f);
  const int2 z = make_int2(0, 0);
  for (int jb = beg; jb < end; jb += 16) {
    const int j0 = jb + g, j1 = j0 + 4, j2 = j0 + 8, j3 = j0 + 12;
    int2 p0 = (j0 < end) ? payload[j0] : z;
    int2 p1 = (j1 < end) ? payload[j1] : z;
    int2 p2 = (j2 < end) ? payload[j2] : z;
    int2 p3 = (j3 < end) ? payload[j3] : z;
    float4 v0 = *(const float4*)(in + (size_t)p0.x * NCH + cq);
    float4 v1 = *(const float4*)(in + (size_t)p1.x * NCH + cq);
    float4 v2 = *(const float4*)(in + (size_t)p2.x * NCH + cq);
    float4 v3 = *(const float4*)(in + (size_t)p3.x * NCH + cq);
    const float a0 = __int_as_float(p0.y), a1 = __int_as_float(p1.y);
    const float a2 = __int_as_float(p2.y), a3 = __int_as_float(p3.y);
    acc.x = __builtin_fmaf(v0.x, a0, acc.x);
    acc.y = __builtin_fmaf(v0.y, a0, acc.y);
    acc.z = __builtin_fmaf(v0.z, a0, acc.z);
    acc.w = __builtin_fmaf(v0.w, a0, acc.w);
    acc.x = __builtin_fmaf(v1.x, a1, acc.x);
    acc.y = __builtin_fmaf(v1.y, a1, acc.y);
    acc.z = __builtin_fmaf(v1.z, a1, acc.z);
    acc.w = __builtin_fmaf(v1.w, a1, acc.w);
    acc.x = __builtin_fmaf(v2.x, a2, acc.x);
    acc.y = __builtin_fmaf(v2.y, a2, acc.y);
    acc.z = __builtin_fmaf(v2.z, a2, acc.z);
    acc.w = __builtin_fmaf(v2.w, a2, acc.w);
    acc.x = __builtin_fmaf(v3.x, a3, acc.x);
    acc.y = __builtin_fmaf(v3.y, a3, acc.y);
    acc.z = __builtin_fmaf(v3.z, a3, acc.z);
    acc.w = __builtin_fmaf(v3.w, a3, acc.w);
  }
  // reduce the 4 edge-groups: lanes l ^ 16 ^ 32 hold the partial sums
#pragma unroll
  for (int off = 16; off <= 32; off <<= 1) {
    acc.x += __shfl_xor(acc.x, off, 64);
    acc.y += __shfl_xor(acc.y, off, 64);
    acc.z += __shfl_xor(acc.z, off, 64);
    acc.w += __shfl_xor(acc.w, off, 64);
  }
  if (g == 0) *(float4*)(out + (size_t)wid * NCH + cq) = acc;
}

// ---------------------------------------------------------------------------
// Fused per-node GEMM: out = h @ Wr + g @ Wn + bias.
// One wave per row; both 64x64 weights in registers; readlane broadcast.
// ---------------------------------------------------------------------------
__global__ __launch_bounds__(256) void node_gemm2_kernel(
    const float* __restrict__ h, const float* __restrict__ g,
    const float* __restrict__ Wr, const float* __restrict__ Wn,
    const float* __restrict__ bias, float* __restrict__ out, int n) {
  const int lane = threadIdx.x & 63;

  float wr[64], wn[64];
#pragma unroll
  for (int k = 0; k < 64; ++k) {
    wr[k] = Wr[k * NCH + lane];
    wn[k] = Wn[k * NCH + lane];
  }
  const float bv = bias[lane];

  const int wave = (blockIdx.x * blockDim.x + threadIdx.x) >> 6;
  const int nwaves = (gridDim.x * blockDim.x) >> 6;

  for (int i = wave; i < n; i += nwaves) {
    float hv = h[(size_t)i * NCH + lane];
    float gv = g[(size_t)i * NCH + lane];
    float acc = bv;
#pragma unroll
    for (int k = 0; k < 64; ++k) {
      acc = __builtin_fmaf(
          __uint_as_float(__builtin_amdgcn_readlane(__float_as_uint(hv), k)),
          wr[k], acc);
      acc = __builtin_fmaf(
          __uint_as_float(__builtin_amdgcn_readlane(__float_as_uint(gv), k)),
          wn[k], acc);
    }
    out[(size_t)i * NCH + lane] = acc;
  }
}

extern "C" void kernel_launch(void* const* d_in, const int* in_sizes, int n_in,
                              void* d_out, int out_size, void* d_ws,
                              size_t ws_size, hipStream_t stream) {
  const float* x = (const float*)d_in[0];
  const float* W1r = (const float*)d_in[1];
  const float* W1n = (const float*)d_in[2];
  const float* b1 = (const float*)d_in[3];
  const float* W2r = (const float*)d_in[4];
  const float* W2n = (const float*)d_in[5];
  const float* b2 = (const float*)d_in[6];
  const int* pool_src = (const int*)d_in[7];
  const int* pool_dst = (const int*)d_in[8];
  const float* pool_attr = (const float*)d_in[9];
  const int* conv_src = (const int*)d_in[10];
  const int* conv_dst = (const int*)d_in[11];
  const float* conv_attr = (const float*)d_in[12];
  const int* unpool_src = (const int*)d_in[13];
  const int* unpool_dst = (const int*)d_in[14];
  const float* unpool_attr = (const float*)d_in[15];

  const int Ep = in_sizes[7];
  const int Ec = in_sizes[10];
  const int Eu = in_sizes[13];
  const int NC = 100000;  // n_coarse (fixed)
  const int NF = 400000;  // n_fine

  const size_t MiB = 1024u * 1024u;

  // ws (~37.2 MiB used; round-2 proved this fits): bufA + unpool CSR.
  char* ws = (char*)d_ws;
  float* bufA = (float*)ws;                // 24.4 MiB
  int* up_rp = (int*)(ws + 26 * MiB);      // 1.6 MiB
  int2* up_pl = (int2*)(ws + 28 * MiB);    // 9.2 MiB

  // d_out doubles as scratch for everything dead before the final unpool
  // gather (which overwrites every row of d_out).
  char* ob = (char*)d_out;
  float* bufB = (float*)ob;                // 24.4 MiB
  float* bufC = (float*)(ob + 26 * MiB);   // 24.4 MiB
  int* cv_rp = (int*)(ob + 52 * MiB);      // 0.4 MiB
  int2* cv_pl = (int2*)(ob + 53 * MiB);    // 12.2 MiB
  int* pl_rp = (int*)(ob + 66 * MiB);      // 0.4 MiB
  int2* pl_pl = (int2*)(ob + 67 * MiB);    // 9.2 MiB
  int* cursor = (int*)(ob + 77 * MiB);     // 1.6 MiB
  int* bsums = (int*)(ob + 79 * MiB);      // ~1 KiB

  const dim3 blk(256);

  auto build_csr = [&](const int* srcA, const int* dstA, const float* attrA,
                       int nE, int nDst, int* rp, int2* pl) {
    int nB = (nDst + 1 + 2047) / 2048;
    hipMemsetAsync(rp, 0, (size_t)(nDst + 1) * sizeof(int), stream);
    hist_kernel<<<dim3((nE + 255) / 256), blk, 0, stream>>>(dstA, rp, nE);
    scan_reduce<<<dim3(nB), blk, 0, stream>>>(rp, bsums, nDst);
    scan_bsums<<<dim3(1), dim3(64), 0, stream>>>(bsums, nB);
    scan_final<<<dim3(nB), blk, 0, stream>>>(rp, bsums, nDst);
    hipMemcpyAsync(cursor, rp, (size_t)nDst * sizeof(int),
                   hipMemcpyDeviceToDevice, stream);
    permute_kernel<<<dim3((nE + 255) / 256), blk, 0, stream>>>(
        srcA, dstA, attrA, cursor, pl, nE);
  };

  build_csr(pool_src, pool_dst, pool_attr, Ep, NC, pl_rp, pl_pl);
  build_csr(conv_src, conv_dst, conv_attr, Ec, NC, cv_rp, cv_pl);
  build_csr(unpool_src, unpool_dst, unpool_attr, Eu, NF, up_rp, up_pl);

  const int gemm_grid = 2048;
  const dim3 gNC((NC + 3) / 4), gNF((NF + 3) / 4);

  // 1. pool: xc = gather(x) -> bufA
  gather4_kernel<<<gNC, blk, 0, stream>>>(x, pl_rp, pl_pl, bufA, NC);

  // 2. conv1: g1 = gather(xc) -> bufB; h1 = xc@W1r + g1@W1n + b1 -> bufC
  gather4_kernel<<<gNC, blk, 0, stream>>>(bufA, cv_rp, cv_pl, bufB, NC);
  node_gemm2_kernel<<<dim3(gemm_grid), blk, 0, stream>>>(bufA, bufB, W1r, W1n,
                                                         b1, bufC, NC);

  // 3. conv2: g2 = gather(h1) -> bufB; h2 = h1@W2r + g2@W2n + b2 -> bufA
  gather4_kernel<<<gNC, blk, 0, stream>>>(bufC, cv_rp, cv_pl, bufB, NC);
  node_gemm2_kernel<<<dim3(gemm_grid), blk, 0, stream>>>(bufC, bufB, W2r, W2n,
                                                         b2, bufA, NC);

  // 4. unpool: d_out = gather(h2); writes every row (zeros for empty segs),
  //    reads only ws -> safe to overwrite all the d_out scratch.
  gather4_kernel<<<gNF, blk, 0, stream>>>(bufA, up_rp, up_pl, (float*)d_out,
                                          NF);
}

// Round 6
// 876.927 us; speedup vs baseline: 1.7382x; 1.1977x over previous
//
#include <hip/hip_runtime.h>

// ConvBlock5: pool -> conv x2 -> unpool, C=64 fp32.
// Round 4 experiment, submission #3 (two prior container-level infra failures;
// source re-audited for OOB/alignment/capture hazards -- none found; rounds
// 2-3 proved the identical scratch scheme).
//
// Change under test: atomic-free permute. Round-3 profile: permute_kernel
// 125us x3 with WRITE_SIZE == 64B * nE -- the cursor atomicAdd is a
// fabric-level 64B RMW (device-scope atomics bypass the non-coherent per-XCD
// L2) and the payload write depends on its return (MLP=1 latency chain).
// Fix: hist pass already performs the identical atomicAdd -- keep its return
// as rank[e]; placement becomes p = rowptr[dst[e]] + rank[e], no atomics.

#define NCH 64

// ---------------------------------------------------------------------------
// CSR build: hist(+rank) -> 3-kernel exclusive scan (in-place) -> place
// ---------------------------------------------------------------------------

// rank[e] = running count of edges with the same dst. 4 edges/thread,
// 4 independent atomics in flight; rank write is coalesced fire-and-forget.
__global__ __launch_bounds__(256) void hist_rank_kernel(
    const int* __restrict__ dst, int* __restrict__ cnt, int* __restrict__ rank,
    int nE) {
  int t = blockIdx.x * blockDim.x + threadIdx.x;
  int e0 = t * 4;
  if (e0 + 3 < nE) {
    int4 d = *(const int4*)(dst + e0);
    int r0 = atomicAdd(&cnt[d.x], 1);
    int r1 = atomicAdd(&cnt[d.y], 1);
    int r2 = atomicAdd(&cnt[d.z], 1);
    int r3 = atomicAdd(&cnt[d.w], 1);
    *(int4*)(rank + e0) = make_int4(r0, r1, r2, r3);
  } else {
    for (int e = e0; e < nE; ++e) rank[e] = atomicAdd(&cnt[dst[e]], 1);
  }
}

static __device__ __forceinline__ int wave_incl_scan(int v, int lane) {
#pragma unroll
  for (int off = 1; off < 64; off <<= 1) {
    int t = __shfl_up(v, off, 64);
    if (lane >= off) v += t;
  }
  return v;
}

__global__ __launch_bounds__(256) void scan_reduce(const int* __restrict__ cnt,
                                                   int* __restrict__ bsums,
                                                   int n) {
  int base = blockIdx.x * 2048 + threadIdx.x * 8;
  int s = 0;
#pragma unroll
  for (int j = 0; j < 8; ++j) {
    int idx = base + j;
    s += (idx < n) ? cnt[idx] : 0;
  }
  int lane = threadIdx.x & 63;
  int w = threadIdx.x >> 6;
#pragma unroll
  for (int off = 32; off; off >>= 1) s += __shfl_xor(s, off, 64);
  __shared__ int ws_[4];
  if (lane == 0) ws_[w] = s;
  __syncthreads();
  if (threadIdx.x == 0) bsums[blockIdx.x] = ws_[0] + ws_[1] + ws_[2] + ws_[3];
}

__global__ void scan_bsums(int* __restrict__ bs, int nB) {
  int lane = threadIdx.x;  // 64 threads
  int carry = 0;
  for (int base = 0; base < nB; base += 64) {
    int i = base + lane;
    int orig = (i < nB) ? bs[i] : 0;
    int v = wave_incl_scan(orig, lane);
    if (i < nB) bs[i] = v - orig + carry;
    carry += __shfl(v, 63, 64);
  }
}

__global__ __launch_bounds__(256) void scan_final(int* __restrict__ cnt_rowptr,
                                                  const int* __restrict__ bsums,
                                                  int n) {
  int base = blockIdx.x * 2048 + threadIdx.x * 8;
  int v[8];
  int s = 0;
#pragma unroll
  for (int j = 0; j < 8; ++j) {
    int idx = base + j;
    v[j] = (idx < n) ? cnt_rowptr[idx] : 0;
    s += v[j];
  }
  int lane = threadIdx.x & 63;
  int w = threadIdx.x >> 6;
  int inc = wave_incl_scan(s, lane);
  __shared__ int wsum[4];
  if (lane == 63) wsum[w] = inc;
  __syncthreads();
  int woff = 0;
  for (int ww = 0; ww < w; ++ww) woff += wsum[ww];
  int excl = inc - s + woff + bsums[blockIdx.x];
#pragma unroll
  for (int j = 0; j < 8; ++j) {
    int idx = base + j;
    if (idx <= n) cnt_rowptr[idx] = excl;
    excl += v[j];
  }
}

// Atomic-free placement: p = rowptr[dst] + rank. 4 edges/thread, vectorized
// 16B reads; rowptr reads are random but L2-resident (<=1.6MB).
__global__ __launch_bounds__(256) void place_kernel(
    const int* __restrict__ src, const int* __restrict__ dst,
    const float* __restrict__ attr, const int* __restrict__ rp,
    const int* __restrict__ rank, int2* __restrict__ payload, int nE) {
  int t = blockIdx.x * blockDim.x + threadIdx.x;
  int e0 = t * 4;
  if (e0 + 3 < nE) {
    int4 s = *(const int4*)(src + e0);
    int4 d = *(const int4*)(dst + e0);
    float4 a = *(const float4*)(attr + e0);
    int4 r = *(const int4*)(rank + e0);
    payload[rp[d.x] + r.x] = make_int2(s.x, __float_as_int(a.x));
    payload[rp[d.y] + r.y] = make_int2(s.y, __float_as_int(a.y));
    payload[rp[d.z] + r.z] = make_int2(s.z, __float_as_int(a.z));
    payload[rp[d.w] + r.w] = make_int2(s.w, __float_as_int(a.w));
  } else {
    for (int e = e0; e < nE; ++e)
      payload[rp[dst[e]] + rank[e]] =
          make_int2(src[e], __float_as_int(attr[e]));
  }
}

// ---------------------------------------------------------------------------
// Gather-reduce, MLP=4: one wave per dst node; 16 lanes/edge, float4/lane.
// ---------------------------------------------------------------------------
__global__ __launch_bounds__(256) void gather4_kernel(
    const float* __restrict__ in, const int* __restrict__ rowptr,
    const int2* __restrict__ payload, float* __restrict__ out, int nDst) {
  const int wid = (blockIdx.x * blockDim.x + threadIdx.x) >> 6;
  const int lane = threadIdx.x & 63;
  if (wid >= nDst) return;
  const int beg = rowptr[wid];
  const int end = rowptr[wid + 1];
  const int g = lane >> 4;         // edge group 0..3
  const int cq = (lane & 15) * 4;  // channel quad base

  float4 acc = make_float4(0.f, 0.f, 0.f, 0.f);
  const int2 z = make_int2(0, 0);
  for (int jb = beg; jb < end; jb += 16) {
    const int j0 = jb + g, j1 = j0 + 4, j2 = j0 + 8, j3 = j0 + 12;
    int2 p0 = (j0 < end) ? payload[j0] : z;
    int2 p1 = (j1 < end) ? payload[j1] : z;
    int2 p2 = (j2 < end) ? payload[j2] : z;
    int2 p3 = (j3 < end) ? payload[j3] : z;
    float4 v0 = *(const float4*)(in + (size_t)p0.x * NCH + cq);
    float4 v1 = *(const float4*)(in + (size_t)p1.x * NCH + cq);
    float4 v2 = *(const float4*)(in + (size_t)p2.x * NCH + cq);
    float4 v3 = *(const float4*)(in + (size_t)p3.x * NCH + cq);
    const float a0 = __int_as_float(p0.y), a1 = __int_as_float(p1.y);
    const float a2 = __int_as_float(p2.y), a3 = __int_as_float(p3.y);
    acc.x = __builtin_fmaf(v0.x, a0, acc.x);
    acc.y = __builtin_fmaf(v0.y, a0, acc.y);
    acc.z = __builtin_fmaf(v0.z, a0, acc.z);
    acc.w = __builtin_fmaf(v0.w, a0, acc.w);
    acc.x = __builtin_fmaf(v1.x, a1, acc.x);
    acc.y = __builtin_fmaf(v1.y, a1, acc.y);
    acc.z = __builtin_fmaf(v1.z, a1, acc.z);
    acc.w = __builtin_fmaf(v1.w, a1, acc.w);
    acc.x = __builtin_fmaf(v2.x, a2, acc.x);
    acc.y = __builtin_fmaf(v2.y, a2, acc.y);
    acc.z = __builtin_fmaf(v2.z, a2, acc.z);
    acc.w = __builtin_fmaf(v2.w, a2, acc.w);
    acc.x = __builtin_fmaf(v3.x, a3, acc.x);
    acc.y = __builtin_fmaf(v3.y, a3, acc.y);
    acc.z = __builtin_fmaf(v3.z, a3, acc.z);
    acc.w = __builtin_fmaf(v3.w, a3, acc.w);
  }
#pragma unroll
  for (int off = 16; off <= 32; off <<= 1) {
    acc.x += __shfl_xor(acc.x, off, 64);
    acc.y += __shfl_xor(acc.y, off, 64);
    acc.z += __shfl_xor(acc.z, off, 64);
    acc.w += __shfl_xor(acc.w, off, 64);
  }
  if (g == 0) *(float4*)(out + (size_t)wid * NCH + cq) = acc;
}

// ---------------------------------------------------------------------------
// Fused per-node GEMM: out = h @ Wr + g @ Wn + bias.
// ---------------------------------------------------------------------------
__global__ __launch_bounds__(256) void node_gemm2_kernel(
    const float* __restrict__ h, const float* __restrict__ g,
    const float* __restrict__ Wr, const float* __restrict__ Wn,
    const float* __restrict__ bias, float* __restrict__ out, int n) {
  const int lane = threadIdx.x & 63;

  float wr[64], wn[64];
#pragma unroll
  for (int k = 0; k < 64; ++k) {
    wr[k] = Wr[k * NCH + lane];
    wn[k] = Wn[k * NCH + lane];
  }
  const float bv = bias[lane];

  const int wave = (blockIdx.x * blockDim.x + threadIdx.x) >> 6;
  const int nwaves = (gridDim.x * blockDim.x) >> 6;

  for (int i = wave; i < n; i += nwaves) {
    float hv = h[(size_t)i * NCH + lane];
    float gv = g[(size_t)i * NCH + lane];
    float acc = bv;
#pragma unroll
    for (int k = 0; k < 64; ++k) {
      acc = __builtin_fmaf(
          __uint_as_float(__builtin_amdgcn_readlane(__float_as_uint(hv), k)),
          wr[k], acc);
      acc = __builtin_fmaf(
          __uint_as_float(__builtin_amdgcn_readlane(__float_as_uint(gv), k)),
          wn[k], acc);
    }
    out[(size_t)i * NCH + lane] = acc;
  }
}

extern "C" void kernel_launch(void* const* d_in, const int* in_sizes, int n_in,
                              void* d_out, int out_size, void* d_ws,
                              size_t ws_size, hipStream_t stream) {
  const float* x = (const float*)d_in[0];
  const float* W1r = (const float*)d_in[1];
  const float* W1n = (const float*)d_in[2];
  const float* b1 = (const float*)d_in[3];
  const float* W2r = (const float*)d_in[4];
  const float* W2n = (const float*)d_in[5];
  const float* b2 = (const float*)d_in[6];
  const int* pool_src = (const int*)d_in[7];
  const int* pool_dst = (const int*)d_in[8];
  const float* pool_attr = (const float*)d_in[9];
  const int* conv_src = (const int*)d_in[10];
  const int* conv_dst = (const int*)d_in[11];
  const float* conv_attr = (const float*)d_in[12];
  const int* unpool_src = (const int*)d_in[13];
  const int* unpool_dst = (const int*)d_in[14];
  const float* unpool_attr = (const float*)d_in[15];

  const int Ep = in_sizes[7];
  const int Ec = in_sizes[10];
  const int Eu = in_sizes[13];
  const int NC = 100000;  // n_coarse (fixed)
  const int NF = 400000;  // n_fine

  const size_t MiB = 1024u * 1024u;

  // ws (~37.2 MiB used): bufA + unpool CSR (must survive into final gather).
  char* ws = (char*)d_ws;
  float* bufA = (float*)ws;              // 24.4 MiB
  int* up_rp = (int*)(ws + 26 * MiB);    // 1.6 MiB
  int2* up_pl = (int2*)(ws + 28 * MiB);  // 9.2 MiB

  // d_out (97.6 MiB) = scratch for everything dead before the final unpool
  // gather (which overwrites every row of d_out).
  char* ob = (char*)d_out;
  float* bufB = (float*)ob;               // 24.4 MiB
  float* bufC = (float*)(ob + 26 * MiB);  // 24.4 MiB
  int* cv_rp = (int*)(ob + 52 * MiB);     // 0.4 MiB
  int2* cv_pl = (int2*)(ob + 53 * MiB);   // 12.2 MiB
  int* pl_rp = (int*)(ob + 66 * MiB);     // 0.4 MiB
  int2* pl_pl = (int2*)(ob + 67 * MiB);   // 9.2 MiB
  int* rank = (int*)(ob + 77 * MiB);      // 6.1 MiB (max Ec ints; reused)
  int* bsums = (int*)(ob + 84 * MiB);     // ~1 KiB

  const dim3 blk(256);

  auto build_csr = [&](const int* srcA, const int* dstA, const float* attrA,
                       int nE, int nDst, int* rp, int2* pl) {
    int nB = (nDst + 1 + 2047) / 2048;
    int nT4 = (nE + 3) / 4;  // threads at 4 edges each
    hipMemsetAsync(rp, 0, (size_t)(nDst + 1) * sizeof(int), stream);
    hist_rank_kernel<<<dim3((nT4 + 255) / 256), blk, 0, stream>>>(dstA, rp,
                                                                  rank, nE);
    scan_reduce<<<dim3(nB), blk, 0, stream>>>(rp, bsums, nDst);
    scan_bsums<<<dim3(1), dim3(64), 0, stream>>>(bsums, nB);
    scan_final<<<dim3(nB), blk, 0, stream>>>(rp, bsums, nDst);
    place_kernel<<<dim3((nT4 + 255) / 256), blk, 0, stream>>>(
        srcA, dstA, attrA, rp, rank, pl, nE);
  };

  build_csr(pool_src, pool_dst, pool_attr, Ep, NC, pl_rp, pl_pl);
  build_csr(conv_src, conv_dst, conv_attr, Ec, NC, cv_rp, cv_pl);
  build_csr(unpool_src, unpool_dst, unpool_attr, Eu, NF, up_rp, up_pl);

  const int gemm_grid = 2048;
  const dim3 gNC((NC + 3) / 4), gNF((NF + 3) / 4);

  // 1. pool: xc = gather(x) -> bufA
  gather4_kernel<<<gNC, blk, 0, stream>>>(x, pl_rp, pl_pl, bufA, NC);

  // 2. conv1: g1 = gather(xc) -> bufB; h1 = xc@W1r + g1@W1n + b1 -> bufC
  gather4_kernel<<<gNC, blk, 0, stream>>>(bufA, cv_rp, cv_pl, bufB, NC);
  node_gemm2_kernel<<<dim3(gemm_grid), blk, 0, stream>>>(bufA, bufB, W1r, W1n,
                                                         b1, bufC, NC);

  // 3. conv2: g2 = gather(h1) -> bufB; h2 = h1@W2r + g2@W2n + b2 -> bufA
  gather4_kernel<<<gNC, blk, 0, stream>>>(bufC, cv_rp, cv_pl, bufB, NC);
  node_gemm2_kernel<<<dim3(gemm_grid), blk, 0, stream>>>(bufC, bufB, W2r, W2n,
                                                         b2, bufA, NC);

  // 4. unpool: d_out = gather(h2); writes every row (zeros for empty segs),
  //    reads only ws -> safe to overwrite all the d_out scratch.
  gather4_kernel<<<gNF, blk, 0, stream>>>(bufA, up_rp, up_pl, (float*)d_out,
                                          NF);
}